// Round 2
// baseline (326.611 us; speedup 1.0000x reference)
//
#include <hip/hip_runtime.h>
#include <hip/hip_bf16.h>

// DeepFM: B=16384, F_DENSE=13, F_SPARSE=26, E=16, V=100000, HID=[512,256]
// MLP is fully affine and only h.sum(axis=1) is used -> collapses exactly to
// h0 . w_eff + scalarC.  Main kernel: 4 lanes/row, float4 gathers (one
// dwordx4 per lane, 4 lanes = one 64B line per (row,field,table)).
// Xi/Xv rows + broadcast tables staged in LDS to kill redundant loads.

#define B_     16384
#define FD_    13
#define FS_    26
#define F_     39
#define E_     16
#define V_     100000
#define H1_    512
#define H2_    256
#define DIN_   624
#define INV_   0.9999950000374998f   // float(1/sqrt(1+1e-5))

#define ROWS_PB 32            // rows per block
#define TPB     128           // 4 lanes per row

// ---------------- precompute kernels ----------------

__global__ void k_v2(const float* __restrict__ Lw2, const float* __restrict__ g2,
                     float* __restrict__ v2) {
    int i = blockIdx.x;
    int l = threadIdx.x;
    float acc = 0.f;
#pragma unroll
    for (int t = 0; t < 4; ++t) {
        int j = t * 64 + l;
        acc += Lw2[i * H2_ + j] * g2[j];
    }
#pragma unroll
    for (int off = 32; off >= 1; off >>= 1)
        acc += __shfl_xor(acc, off, 64);
    if (l == 0) v2[i] = acc * INV_;
}

__global__ void k_weff(const float* __restrict__ Lw1, const float* __restrict__ g1,
                       const float* __restrict__ v2, float* __restrict__ w_eff) {
    __shared__ float red[4];
    int k = blockIdx.x;
    int t = threadIdx.x;
    float acc = Lw1[k * H1_ + t]       * g1[t]       * v2[t]
              + Lw1[k * H1_ + t + 256] * g1[t + 256] * v2[t + 256];
#pragma unroll
    for (int off = 32; off >= 1; off >>= 1)
        acc += __shfl_xor(acc, off, 64);
    if ((t & 63) == 0) red[t >> 6] = acc;
    __syncthreads();
    if (t == 0)
        w_eff[k] = (red[0] + red[1] + red[2] + red[3]) * INV_;
}

__global__ void k_scalar(const float* __restrict__ Lb1, const float* __restrict__ g1,
                         const float* __restrict__ be1, const float* __restrict__ v2,
                         const float* __restrict__ Lb2, const float* __restrict__ g2,
                         const float* __restrict__ be2, float* __restrict__ scalarC) {
    __shared__ float red[8];
    int t = threadIdx.x;
    float val = (Lb1[t] * INV_ * g1[t] + be1[t]) * v2[t];
    if (t < H2_)
        val += Lb2[t] * INV_ * g2[t] + be2[t];
#pragma unroll
    for (int off = 32; off >= 1; off >>= 1)
        val += __shfl_xor(val, off, 64);
    if ((t & 63) == 0) red[t >> 6] = val;
    __syncthreads();
    if (t == 0) {
        float s = 0.f;
#pragma unroll
        for (int w = 0; w < 8; ++w) s += red[w];
        scalarC[0] = s;
    }
}

// ---------------- main kernel ----------------
// Block: 128 threads = 32 rows x 4 lanes.  Lane r covers e = 4r..4r+3 (float4).
// LDS: packed tables [W1|b1|W2|b2|w_eff] (1456 f) + Xi/Xv rows (2x1248).
__global__ __launch_bounds__(TPB) void k_main(
        const int*   __restrict__ Xi,
        const float* __restrict__ Xv,
        const float* __restrict__ W1,  const float* __restrict__ b1,
        const float* __restrict__ emb1,
        const float* __restrict__ W2,  const float* __restrict__ b2,
        const float* __restrict__ emb2,
        const float* __restrict__ bias,
        const float* __restrict__ w_eff,
        const float* __restrict__ scalarC,
        float* __restrict__ out) {
    __shared__ __align__(16) float sTab[832 + DIN_];   // W1|b1|W2|b2 (4*208) | w_eff (624)
    __shared__ int   sXi[ROWS_PB * F_];
    __shared__ float sXv[ROWS_PB * F_];

    const int tid = threadIdx.x;
    const int r   = tid & 3;          // lane within row (e-quad)
    const int rl  = tid >> 2;         // local row
    const int row = blockIdx.x * ROWS_PB + rl;

    // ---- stage broadcast tables ----
    for (int i = tid; i < 208; i += TPB) {
        sTab[i]       = W1[i];
        sTab[208 + i] = b1[i];
        sTab[416 + i] = W2[i];
        sTab[624 + i] = b2[i];
    }
    for (int i = tid; i < DIN_; i += TPB)
        sTab[832 + i] = w_eff[i];
    // ---- stage Xi/Xv rows (coalesced) ----
    {
        const int base = blockIdx.x * ROWS_PB * F_;
        for (int i = tid; i < ROWS_PB * F_; i += TPB) {
            sXi[i] = Xi[base + i];
            sXv[i] = Xv[base + i];
        }
    }
    __syncthreads();

    const float4* tab4   = (const float4*)sTab;      // [0,52) W1 | [52,104) b1 | [104,156) W2 | [156,208) b2 | [208,364) w_eff
    const float4* emb1_4 = (const float4*)emb1;
    const float4* emb2_4 = (const float4*)emb2;

    float aFx = 0.f, aFy = 0.f, aFz = 0.f, aFw = 0.f;   // fm_first
    float s1x = 0.f, s1y = 0.f, s1z = 0.f, s1w = 0.f;   // sum_emb
    float s2x = 0.f, s2y = 0.f, s2z = 0.f, s2w = 0.f;   // sumsq
    float aHx = 0.f, aHy = 0.f, aHz = 0.f, aHw = 0.f;   // h0 . w_eff

#pragma unroll
    for (int f = 0; f < FD_; ++f) {
        float  xi = (float)sXi[rl * F_ + f];
        float  xv = sXv[rl * F_ + f];
        float4 w1 = tab4[f * 4 + r];
        float4 bb1 = tab4[52 + f * 4 + r];
        float4 w2 = tab4[104 + f * 4 + r];
        float4 bb2 = tab4[156 + f * 4 + r];
        float4 we = tab4[208 + f * 4 + r];
        float secx = xi * w2.x + bb2.x, secy = xi * w2.y + bb2.y;
        float secz = xi * w2.z + bb2.z, secw = xi * w2.w + bb2.w;
        aFx += (xi * w1.x + bb1.x) * xv;  aFy += (xi * w1.y + bb1.y) * xv;
        aFz += (xi * w1.z + bb1.z) * xv;  aFw += (xi * w1.w + bb1.w) * xv;
        s1x += secx; s1y += secy; s1z += secz; s1w += secw;
        s2x += secx * secx; s2y += secy * secy; s2z += secz * secz; s2w += secw * secw;
        aHx += secx * we.x; aHy += secy * we.y; aHz += secz * we.z; aHw += secw * we.w;
    }

#pragma unroll
    for (int f = 0; f < FS_; ++f) {
        int    id = sXi[rl * F_ + FD_ + f];
        float  xv = sXv[rl * F_ + FD_ + f];
        size_t o  = (size_t)(f * V_ + id) * 4 + r;    // float4 units
        float4 e1 = emb1_4[o];
        float4 e2 = emb2_4[o];
        float4 we = tab4[208 + (FD_ + f) * 4 + r];
        float secx = e2.x * xv, secy = e2.y * xv, secz = e2.z * xv, secw = e2.w * xv;
        aFx += e1.x * xv; aFy += e1.y * xv; aFz += e1.z * xv; aFw += e1.w * xv;
        s1x += secx; s1y += secy; s1z += secz; s1w += secw;
        s2x += secx * secx; s2y += secy * secy; s2z += secz * secz; s2w += secw * secw;
        aHx += secx * we.x; aHy += secy * we.y; aHz += secz * we.z; aHw += secw * we.w;
    }

    float part = (aFx + aHx + 0.5f * (s1x * s1x - s2x))
               + (aFy + aHy + 0.5f * (s1y * s1y - s2y))
               + (aFz + aHz + 0.5f * (s1z * s1z - s2z))
               + (aFw + aHw + 0.5f * (s1w * s1w - s2w));

    part += __shfl_xor(part, 1, 4);
    part += __shfl_xor(part, 2, 4);

    if (r == 0)
        out[row] = part + bias[row] + scalarC[0];
}

extern "C" void kernel_launch(void* const* d_in, const int* in_sizes, int n_in,
                              void* d_out, int out_size, void* d_ws, size_t ws_size,
                              hipStream_t stream) {
    const int*   Xi   = (const int*)  d_in[0];
    const float* Xv   = (const float*)d_in[1];
    const float* W1   = (const float*)d_in[2];
    const float* b1   = (const float*)d_in[3];
    const float* emb1 = (const float*)d_in[4];
    const float* W2   = (const float*)d_in[5];
    const float* b2   = (const float*)d_in[6];
    const float* emb2 = (const float*)d_in[7];
    const float* Lw1  = (const float*)d_in[8];
    const float* Lb1  = (const float*)d_in[9];
    const float* g1   = (const float*)d_in[10];
    const float* be1  = (const float*)d_in[11];
    const float* Lw2  = (const float*)d_in[12];
    const float* Lb2  = (const float*)d_in[13];
    const float* g2   = (const float*)d_in[14];
    const float* be2  = (const float*)d_in[15];
    const float* bias = (const float*)d_in[16];
    float* out = (float*)d_out;

    float* ws      = (float*)d_ws;
    float* v2      = ws;              // 512
    float* w_eff   = ws + 512;        // 624
    float* scalarC = ws + 512 + 624;  // 1

    k_v2    <<<H1_,  64, 0, stream>>>(Lw2, g2, v2);
    k_weff  <<<DIN_, 256, 0, stream>>>(Lw1, g1, v2, w_eff);
    k_scalar<<<1,    512, 0, stream>>>(Lb1, g1, be1, v2, Lb2, g2, be2, scalarC);
    k_main  <<<B_ / ROWS_PB, TPB, 0, stream>>>(
        Xi, Xv, W1, b1, emb1, W2, b2, emb2, bias, w_eff, scalarC, out);
}

// Round 3
// 316.516 us; speedup vs baseline: 1.0319x; 1.0319x over previous
//
#include <hip/hip_runtime.h>
#include <hip/hip_bf16.h>

// DeepFM: B=16384, F_DENSE=13, F_SPARSE=26, E=16, V=100000, HID=[512,256]
// MLP is fully affine and only h.sum(axis=1) is used -> collapses exactly to
// h0 . w_eff + scalarC.
// R3: 8 lanes/row (2 field-groups x 4 e-quads), float4 gathers.
//     131072 threads = 8 waves/CU (2x R2) to hide random-gather latency.

#define B_     16384
#define FD_    13
#define FS_    26
#define F_     39
#define E_     16
#define V_     100000
#define H1_    512
#define H2_    256
#define DIN_   624
#define INV_   0.9999950000374998f   // float(1/sqrt(1+1e-5))

#define ROWS_PB 32            // rows per block
#define TPB     256           // 8 lanes per row

// ---------------- precompute kernels ----------------

__global__ void k_v2(const float* __restrict__ Lw2, const float* __restrict__ g2,
                     float* __restrict__ v2) {
    int i = blockIdx.x;
    int l = threadIdx.x;
    float acc = 0.f;
#pragma unroll
    for (int t = 0; t < 4; ++t) {
        int j = t * 64 + l;
        acc += Lw2[i * H2_ + j] * g2[j];
    }
#pragma unroll
    for (int off = 32; off >= 1; off >>= 1)
        acc += __shfl_xor(acc, off, 64);
    if (l == 0) v2[i] = acc * INV_;
}

__global__ void k_weff(const float* __restrict__ Lw1, const float* __restrict__ g1,
                       const float* __restrict__ v2, float* __restrict__ w_eff) {
    __shared__ float red[4];
    int k = blockIdx.x;
    int t = threadIdx.x;
    float acc = Lw1[k * H1_ + t]       * g1[t]       * v2[t]
              + Lw1[k * H1_ + t + 256] * g1[t + 256] * v2[t + 256];
#pragma unroll
    for (int off = 32; off >= 1; off >>= 1)
        acc += __shfl_xor(acc, off, 64);
    if ((t & 63) == 0) red[t >> 6] = acc;
    __syncthreads();
    if (t == 0)
        w_eff[k] = (red[0] + red[1] + red[2] + red[3]) * INV_;
}

__global__ void k_scalar(const float* __restrict__ Lb1, const float* __restrict__ g1,
                         const float* __restrict__ be1, const float* __restrict__ v2,
                         const float* __restrict__ Lb2, const float* __restrict__ g2,
                         const float* __restrict__ be2, float* __restrict__ scalarC) {
    __shared__ float red[8];
    int t = threadIdx.x;
    float val = (Lb1[t] * INV_ * g1[t] + be1[t]) * v2[t];
    if (t < H2_)
        val += Lb2[t] * INV_ * g2[t] + be2[t];
#pragma unroll
    for (int off = 32; off >= 1; off >>= 1)
        val += __shfl_xor(val, off, 64);
    if ((t & 63) == 0) red[t >> 6] = val;
    __syncthreads();
    if (t == 0) {
        float s = 0.f;
#pragma unroll
        for (int w = 0; w < 8; ++w) s += red[w];
        scalarC[0] = s;
    }
}

// ---------------- main kernel ----------------
// Block: 256 threads = 32 rows x 8 lanes.
// Lane l = (g, r): g = field-group (even/odd fields), r = e-quad (float4).
// Each lane: 13 sparse fields x 2 tables = 26 float4 gathers.
__global__ __launch_bounds__(TPB) void k_main(
        const int*   __restrict__ Xi,
        const float* __restrict__ Xv,
        const float* __restrict__ W1,  const float* __restrict__ b1,
        const float* __restrict__ emb1,
        const float* __restrict__ W2,  const float* __restrict__ b2,
        const float* __restrict__ emb2,
        const float* __restrict__ bias,
        const float* __restrict__ w_eff,
        const float* __restrict__ scalarC,
        float* __restrict__ out) {
    __shared__ __align__(16) float sTab[832 + DIN_];   // W1|b1|W2|b2 (4*208) | w_eff (624)
    __shared__ int   sXi[ROWS_PB * F_];
    __shared__ float sXv[ROWS_PB * F_];

    const int tid = threadIdx.x;
    const int r   = tid & 3;          // e-quad
    const int g   = (tid >> 2) & 1;   // field group (f % 2 == g)
    const int rl  = tid >> 3;         // local row
    const int row = blockIdx.x * ROWS_PB + rl;

    // ---- stage broadcast tables ----
    for (int i = tid; i < 208; i += TPB) {
        sTab[i]       = W1[i];
        sTab[208 + i] = b1[i];
        sTab[416 + i] = W2[i];
        sTab[624 + i] = b2[i];
    }
    for (int i = tid; i < DIN_; i += TPB)
        sTab[832 + i] = w_eff[i];
    // ---- stage Xi/Xv rows (coalesced) ----
    {
        const int base = blockIdx.x * ROWS_PB * F_;
        for (int i = tid; i < ROWS_PB * F_; i += TPB) {
            sXi[i] = Xi[base + i];
            sXv[i] = Xv[base + i];
        }
    }
    __syncthreads();

    const float4* tab4   = (const float4*)sTab;  // [0,52) W1 | [52,104) b1 | [104,156) W2 | [156,208) b2 | [208,364) w_eff
    const float4* emb1_4 = (const float4*)emb1;
    const float4* emb2_4 = (const float4*)emb2;

    float aFx = 0.f, aFy = 0.f, aFz = 0.f, aFw = 0.f;   // fm_first partial
    float s1x = 0.f, s1y = 0.f, s1z = 0.f, s1w = 0.f;   // sum_emb partial
    float s2x = 0.f, s2y = 0.f, s2z = 0.f, s2w = 0.f;   // sumsq partial
    float aHx = 0.f, aHy = 0.f, aHz = 0.f, aHw = 0.f;   // h0 . w_eff partial

    // ---- dense fields: f = g, g+2, ... (< 13); g=0 -> 7 fields, g=1 -> 6 ----
#pragma unroll
    for (int k = 0; k < 7; ++k) {
        int f = 2 * k + g;
        if (f < FD_) {
            float  xi  = (float)sXi[rl * F_ + f];
            float  xv  = sXv[rl * F_ + f];
            float4 w1  = tab4[f * 4 + r];
            float4 bb1 = tab4[52 + f * 4 + r];
            float4 w2  = tab4[104 + f * 4 + r];
            float4 bb2 = tab4[156 + f * 4 + r];
            float4 we  = tab4[208 + f * 4 + r];
            float secx = xi * w2.x + bb2.x, secy = xi * w2.y + bb2.y;
            float secz = xi * w2.z + bb2.z, secw = xi * w2.w + bb2.w;
            aFx += (xi * w1.x + bb1.x) * xv;  aFy += (xi * w1.y + bb1.y) * xv;
            aFz += (xi * w1.z + bb1.z) * xv;  aFw += (xi * w1.w + bb1.w) * xv;
            s1x += secx; s1y += secy; s1z += secz; s1w += secw;
            s2x += secx * secx; s2y += secy * secy; s2z += secz * secz; s2w += secw * secw;
            aHx += secx * we.x; aHy += secy * we.y; aHz += secz * we.z; aHw += secw * we.w;
        }
    }

    // ---- sparse fields: f = g, g+2, ..., g+24 (13 fields each group) ----
#pragma unroll
    for (int k = 0; k < 13; ++k) {
        int    f  = 2 * k + g;
        int    id = sXi[rl * F_ + FD_ + f];
        float  xv = sXv[rl * F_ + FD_ + f];
        size_t o  = (size_t)(f * V_ + id) * 4 + r;    // float4 units
        float4 e1 = emb1_4[o];
        float4 e2 = emb2_4[o];
        float4 we = tab4[208 + (FD_ + f) * 4 + r];
        float secx = e2.x * xv, secy = e2.y * xv, secz = e2.z * xv, secw = e2.w * xv;
        aFx += e1.x * xv; aFy += e1.y * xv; aFz += e1.z * xv; aFw += e1.w * xv;
        s1x += secx; s1y += secy; s1z += secz; s1w += secw;
        s2x += secx * secx; s2y += secy * secy; s2z += secz * secz; s2w += secw * secw;
        aHx += secx * we.x; aHy += secy * we.y; aHz += secz * we.z; aHw += secw * we.w;
    }

    // ---- combine the two field groups' s1 (needed before squaring) ----
    s1x += __shfl_xor(s1x, 4, 8);
    s1y += __shfl_xor(s1y, 4, 8);
    s1z += __shfl_xor(s1z, 4, 8);
    s1w += __shfl_xor(s1w, 4, 8);

    // linear parts stay per-lane (distinct data per (g,r)); quadratic term is
    // duplicated across the two g-halves -> weight 0.5 before the 8-lane sum.
    float lin = (aFx + aHx - 0.5f * s2x) + (aFy + aHy - 0.5f * s2y)
              + (aFz + aHz - 0.5f * s2z) + (aFw + aHw - 0.5f * s2w);
    float q   = 0.5f * (s1x * s1x + s1y * s1y + s1z * s1z + s1w * s1w);
    float part = lin + 0.5f * q;

    part += __shfl_xor(part, 1, 8);
    part += __shfl_xor(part, 2, 8);
    part += __shfl_xor(part, 4, 8);

    if ((tid & 7) == 0)
        out[row] = part + bias[row] + scalarC[0];
}

extern "C" void kernel_launch(void* const* d_in, const int* in_sizes, int n_in,
                              void* d_out, int out_size, void* d_ws, size_t ws_size,
                              hipStream_t stream) {
    const int*   Xi   = (const int*)  d_in[0];
    const float* Xv   = (const float*)d_in[1];
    const float* W1   = (const float*)d_in[2];
    const float* b1   = (const float*)d_in[3];
    const float* emb1 = (const float*)d_in[4];
    const float* W2   = (const float*)d_in[5];
    const float* b2   = (const float*)d_in[6];
    const float* emb2 = (const float*)d_in[7];
    const float* Lw1  = (const float*)d_in[8];
    const float* Lb1  = (const float*)d_in[9];
    const float* g1   = (const float*)d_in[10];
    const float* be1  = (const float*)d_in[11];
    const float* Lw2  = (const float*)d_in[12];
    const float* Lb2  = (const float*)d_in[13];
    const float* g2   = (const float*)d_in[14];
    const float* be2  = (const float*)d_in[15];
    const float* bias = (const float*)d_in[16];
    float* out = (float*)d_out;

    float* ws      = (float*)d_ws;
    float* v2      = ws;              // 512
    float* w_eff   = ws + 512;        // 624
    float* scalarC = ws + 512 + 624;  // 1

    k_v2    <<<H1_,  64, 0, stream>>>(Lw2, g2, v2);
    k_weff  <<<DIN_, 256, 0, stream>>>(Lw1, g1, v2, w_eff);
    k_scalar<<<1,    512, 0, stream>>>(Lb1, g1, be1, v2, Lb2, g2, be2, scalarC);
    k_main  <<<B_ / ROWS_PB, TPB, 0, stream>>>(
        Xi, Xv, W1, b1, emb1, W2, b2, emb2, bias, w_eff, scalarC, out);
}